// Round 1
// baseline (687.482 us; speedup 1.0000x reference)
//
#include <hip/hip_runtime.h>
#include <hip/hip_bf16.h>

#define B_ 512
#define C_ 22
#define TIN 1001
#define K_ 40
#define KS_ 25
#define TO 976
#define TILE 122
#define NTILES 8
#define NBLK (B_ * NTILES) /* 4096 */
#define P_ 100
#define NW 9
#define NOUT 4
#define FCIN (K_ * NW) /* 360 */

__device__ __forceinline__ float waveReduceSum(float v) {
#pragma unroll
  for (int m = 32; m >= 1; m >>= 1) v += __shfl_xor(v, m, 64);
  return v;
}

__global__ void sid_kernel(const float* __restrict__ x, int* __restrict__ sid) {
  int b = blockIdx.x * blockDim.x + threadIdx.x;
  if (b < B_) {
    float v = x[(size_t)b * C_ * TIN + (TIN - 1)];
    sid[b] = (int)rintf(v * 1e-6f) - 1;
  }
}

// grid: 4096 blocks (512 b x 8 t-tiles), 256 threads (4 waves x 64 lanes)
// wave w owns k in [w*10, w*10+10); lane owns t = t0+2*lane, t0+2*lane+1
__global__ __launch_bounds__(256) void conv_kernel(
    const float* __restrict__ x, const float* __restrict__ W,
    const float* __restrict__ bias, const int* __restrict__ sid,
    float* __restrict__ pooled, float* __restrict__ part_sum,
    float* __restrict__ part_sq) {
  const int blk = blockIdx.x;
  const int bb = blk >> 3;
  const int tile = blk & 7;
  const int t0 = tile * TILE;

  __shared__ float xs[C_][TILE + KS_ - 1];  // 22 x 146 = 12.8 KB

  const int s = __builtin_amdgcn_readfirstlane(sid[bb]);
  const float* xb = x + (size_t)bb * C_ * TIN + t0;
  for (int i = threadIdx.x; i < C_ * (TILE + KS_ - 1); i += 256) {
    int c = i / (TILE + KS_ - 1);
    int tt = i - c * (TILE + KS_ - 1);
    xs[c][tt] = xb[c * TIN + tt];
  }
  __syncthreads();

  const int wave = threadIdx.x >> 6;
  const int lane = threadIdx.x & 63;
  const int tl = 2 * lane;
  const bool act0 = (tl < TILE);
  const bool act1 = (tl + 1 < TILE);
  const int tls = act0 ? tl : 0;  // clamp so idle lanes don't read OOB LDS

  float acc0[10], acc1[10];
#pragma unroll
  for (int i = 0; i < 10; ++i) {
    acc0[i] = 0.f;
    acc1[i] = 0.f;
  }

  const float* Ws = W + (((size_t)s * K_) + wave * 10) * (C_ * KS_);

  for (int c = 0; c < C_; ++c) {
    float win[KS_ + 1];
#pragma unroll
    for (int i = 0; i < KS_ + 1; ++i) win[i] = xs[c][tls + i];
#pragma unroll
    for (int kb = 0; kb < 10; ++kb) {
      const float* wp = Ws + kb * (C_ * KS_) + c * KS_;
#pragma unroll
      for (int j = 0; j < KS_; ++j) {
        const float wv = wp[j];
        acc0[kb] = fmaf(wv, win[j], acc0[kb]);
        acc1[kb] = fmaf(wv, win[j + 1], acc1[kb]);
      }
    }
  }

  // epilogue: bias + ELU, BN stats partials, pooling partials
  const int tg0 = t0 + tl, tg1 = t0 + tl + 1;
  const int w0 = tg0 / P_;
  const int w1 = tg1 / P_;
  const int wlo = t0 / P_;
  const bool v0 = act0 && (tg0 < NW * P_);
  const bool v1 = act1 && (tg1 < NW * P_);

#pragma unroll
  for (int kb = 0; kb < 10; ++kb) {
    const int k = wave * 10 + kb;
    const float bv = bias[s * K_ + k];
    float y0 = 0.f, y1 = 0.f;
    if (act0) {
      float v = acc0[kb] + bv;
      y0 = v > 0.f ? v : expm1f(v);
    }
    if (act1) {
      float v = acc1[kb] + bv;
      y1 = v > 0.f ? v : expm1f(v);
    }
    float sy = waveReduceSum(y0 + y1);
    float sq = waveReduceSum(y0 * y0 + y1 * y1);
    float p0 = (v0 && w0 == wlo ? y0 : 0.f) + (v1 && w1 == wlo ? y1 : 0.f);
    float p1 = (v0 && w0 == wlo + 1 ? y0 : 0.f) + (v1 && w1 == wlo + 1 ? y1 : 0.f);
    float p2 = (v0 && w0 == wlo + 2 ? y0 : 0.f) + (v1 && w1 == wlo + 2 ? y1 : 0.f);
    p0 = waveReduceSum(p0);
    p1 = waveReduceSum(p1);
    p2 = waveReduceSum(p2);
    if (lane == 0) {
      part_sum[(size_t)k * NBLK + blk] = sy;
      part_sq[(size_t)k * NBLK + blk] = sq;
      float* pb = pooled + (size_t)bb * FCIN + k * NW;
      atomicAdd(&pb[wlo], p0);
      if (wlo + 1 <= NW - 1 && (wlo + 1) * P_ < t0 + TILE) atomicAdd(&pb[wlo + 1], p1);
      if (wlo + 2 <= NW - 1 && (wlo + 2) * P_ < t0 + TILE) atomicAdd(&pb[wlo + 2], p2);
    }
  }
}

__global__ __launch_bounds__(256) void stats_kernel(
    const float* __restrict__ part_sum, const float* __restrict__ part_sq,
    const float* __restrict__ gamma, const float* __restrict__ beta,
    float* __restrict__ ss) {
  const int k = blockIdx.x;
  float s = 0.f, q = 0.f;
  for (int i = threadIdx.x; i < NBLK; i += 256) {
    s += part_sum[(size_t)k * NBLK + i];
    q += part_sq[(size_t)k * NBLK + i];
  }
  s = waveReduceSum(s);
  q = waveReduceSum(q);
  __shared__ float ls[4], lq[4];
  const int wave = threadIdx.x >> 6, lane = threadIdx.x & 63;
  if (lane == 0) {
    ls[wave] = s;
    lq[wave] = q;
  }
  __syncthreads();
  if (threadIdx.x == 0) {
    float S = ls[0] + ls[1] + ls[2] + ls[3];
    float Q = lq[0] + lq[1] + lq[2] + lq[3];
    const float N = (float)B_ * (float)TO;
    float mean = S / N;
    float var = Q / N - mean * mean;
    float sc = gamma[k] / sqrtf(var + 1e-5f);
    ss[k] = sc;
    ss[K_ + k] = beta[k] - mean * sc;
  }
}

// grid: 512 blocks (one per b), 256 threads: out index n = tid>>6, lanes reduce
__global__ __launch_bounds__(256) void fc_kernel(
    const float* __restrict__ pooled, const float* __restrict__ ss,
    const float* __restrict__ fc_w, const float* __restrict__ fc_b,
    float* __restrict__ out) {
  const int bb = blockIdx.x;
  const int n = threadIdx.x >> 6;
  const int lane = threadIdx.x & 63;
  float acc = 0.f;
  for (int i = lane; i < FCIN; i += 64) {
    const int k = i / NW;
    float y = pooled[(size_t)bb * FCIN + i] * (1.f / (float)P_) * ss[k] + ss[K_ + k];
    acc = fmaf(y, fc_w[n * FCIN + i], acc);
  }
  acc = waveReduceSum(acc);
  if (lane == 0) out[bb * NOUT + n] = acc + fc_b[n];
}

extern "C" void kernel_launch(void* const* d_in, const int* in_sizes, int n_in,
                              void* d_out, int out_size, void* d_ws, size_t ws_size,
                              hipStream_t stream) {
  const float* x = (const float*)d_in[0];
  const float* W = (const float*)d_in[1];
  const float* b = (const float*)d_in[2];
  const float* gamma = (const float*)d_in[3];
  const float* beta = (const float*)d_in[4];
  const float* fc_w = (const float*)d_in[5];
  const float* fc_b = (const float*)d_in[6];
  float* out = (float*)d_out;

  char* ws = (char*)d_ws;
  float* pooled = (float*)ws;                            // B*360
  float* part_sum = pooled + (size_t)B_ * FCIN;          // K*NBLK
  float* part_sq = part_sum + (size_t)K_ * NBLK;         // K*NBLK
  float* ss = part_sq + (size_t)K_ * NBLK;               // 2*K
  int* sid = (int*)(ss + 2 * K_);                        // B

  hipMemsetAsync(pooled, 0, (size_t)B_ * FCIN * sizeof(float), stream);
  sid_kernel<<<2, 256, 0, stream>>>(x, sid);
  conv_kernel<<<NBLK, 256, 0, stream>>>(x, W, b, sid, pooled, part_sum, part_sq);
  stats_kernel<<<K_, 256, 0, stream>>>(part_sum, part_sq, gamma, beta, ss);
  fc_kernel<<<B_, 256, 0, stream>>>(pooled, ss, fc_w, fc_b, out);
}

// Round 2
// 112.400 us; speedup vs baseline: 6.1164x; 6.1164x over previous
//
#include <hip/hip_runtime.h>
#include <hip/hip_bf16.h>

#define B_ 512
#define C_ 22
#define TIN 1001
#define K_ 40
#define KS_ 25
#define TO 976
#define P_ 100
#define NW 9
#define NOUT 4
#define FCIN 360
#define NBLK 4096

#define XT_ROWS 1056
#define XT_BYTES (XT_ROWS * 64)         /* 67584 */
#define WB_STRIDE_J (48 * 64)           /* 3072 bytes per j */
#define WB_BYTES (KS_ * WB_STRIDE_J)    /* 76800 */
#define LDS_TOTAL (XT_BYTES + WB_BYTES) /* 144384 */

typedef __attribute__((ext_vector_type(8))) short bf16x8;
typedef __attribute__((ext_vector_type(4))) float f32x4;
typedef __attribute__((ext_vector_type(4))) int i32x4;

__device__ __forceinline__ float waveReduceSum(float v) {
#pragma unroll
  for (int m = 32; m >= 1; m >>= 1) v += __shfl_xor(v, m, 64);
  return v;
}

__device__ __forceinline__ unsigned short f2bf(float f) {
  __hip_bfloat16 h = __float2bfloat16(f);
  return *reinterpret_cast<unsigned short*>(&h);
}

// Convert W[s][k][c][j] fp32 -> WBg[s][j][n][c] bf16, n padded to 48, c padded
// to 32, with 16B-chunk XOR swizzle on c-chunks: physical chunk q holds
// logical chunk q ^ ((n>>1)&3).
__global__ __launch_bounds__(256) void wconv_kernel(const float* __restrict__ W,
                                                    unsigned short* __restrict__ WBg) {
  const int s = blockIdx.x / KS_;
  const int j = blockIdx.x % KS_;
  const int tid = threadIdx.x;
  if (tid >= 192) return;
  const int n = tid >> 2;
  const int q = tid & 3;                // physical 16B chunk
  const int lq = q ^ ((n >> 1) & 3);    // logical chunk -> c0
  union {
    unsigned short u16[8];
    i32x4 v;
  } pk;
#pragma unroll
  for (int e = 0; e < 8; ++e) {
    const int c = lq * 8 + e;
    float v = 0.f;
    if (n < K_ && c < C_) v = W[(((size_t)s * K_ + n) * C_ + c) * KS_ + j];
    pk.u16[e] = f2bf(v);
  }
  *(i32x4*)(WBg + ((size_t)(s * KS_ + j) * 48 + n) * 32 + q * 8) = pk.v;
}

// One block per sample b. LDS: xT[1056][32] bf16 (swizzled) + WB copy.
// 8 waves; wave wv computes output rows [it*512 + wv*64, +64) for it=0,1.
// k-step = tap j (25 steps of 32 c's). MFMA 16x16x32 bf16.
__global__ __launch_bounds__(512, 1) void conv_kernel(
    const float* __restrict__ x, const unsigned short* __restrict__ WBg,
    const float* __restrict__ bias, float* __restrict__ pooled,
    float* __restrict__ part_sum, float* __restrict__ part_sq) {
  extern __shared__ __align__(16) char smem[];
  const int b = blockIdx.x;
  const int tid = threadIdx.x;

  int s = (int)rintf(x[(size_t)b * C_ * TIN + (TIN - 1)] * 1e-6f) - 1;
  s = __builtin_amdgcn_readfirstlane(min(max(s, 0), 8));

  // Stage WB: linear 16B copy (global layout is already swizzled).
  {
    const i32x4* src = (const i32x4*)(WBg + (size_t)s * (WB_BYTES / 2));
    i32x4* dst = (i32x4*)(smem + XT_BYTES);
    for (int off = tid; off < WB_BYTES / 16; off += 512) dst[off] = src[off];
  }
  // Stage xT: transpose + fp32->bf16 + swizzle. Task (t, physical chunk q).
  {
    const float* xb = x + (size_t)b * C_ * TIN;
    for (int task = tid; task < XT_ROWS * 4; task += 512) {
      const int t = task >> 2;
      const int q = task & 3;
      const int lq = q ^ ((t >> 1) & 3);
      const int c0 = lq * 8;
      union {
        unsigned short u16[8];
        i32x4 v;
      } pk;
#pragma unroll
      for (int e = 0; e < 8; ++e) {
        const int c = c0 + e;
        float v = 0.f;
        if (c < C_ && t < TIN - 1) v = xb[c * TIN + t];
        pk.u16[e] = f2bf(v);
      }
      *(i32x4*)(smem + t * 64 + q * 16) = pk.v;
    }
  }
  __syncthreads();

  const int lane = tid & 63;
  const int wv = tid >> 6;
  const int l15 = lane & 15;
  const int lg = lane >> 4;  // logical c-chunk (k-group)

  // B-operand per-lane base: row n = l15 (+nt*16 -> +nt*1024 bytes), chunk lg
  // swizzled by (n>>1)&3 which is nt-independent.
  const char* wb_base = smem + XT_BYTES + l15 * 64 + ((lg ^ ((l15 >> 1) & 3)) << 4);

  float sY[3] = {0.f, 0.f, 0.f};
  float sY2[3] = {0.f, 0.f, 0.f};
  float bv[3];
#pragma unroll
  for (int nt = 0; nt < 3; ++nt) {
    const int k = nt * 16 + l15;
    bv[nt] = bias[s * K_ + (k < K_ ? k : 0)];
  }

#pragma unroll
  for (int it = 0; it < 2; ++it) {
    const int t0w = it * 512 + wv * 64;
    f32x4 acc[4][3];
#pragma unroll
    for (int m = 0; m < 4; ++m)
#pragma unroll
      for (int nt = 0; nt < 3; ++nt) acc[m][nt] = (f32x4){0.f, 0.f, 0.f, 0.f};

    const int tA = t0w + l15;
    for (int j = 0; j < KS_; ++j) {
      const int t = tA + j;
      const char* ap = smem + t * 64 + ((lg ^ ((t >> 1) & 3)) << 4);
      bf16x8 a0 = *(const bf16x8*)(ap);
      bf16x8 a1 = *(const bf16x8*)(ap + 1024);
      bf16x8 a2 = *(const bf16x8*)(ap + 2048);
      bf16x8 a3 = *(const bf16x8*)(ap + 3072);
      const char* bp = wb_base + j * WB_STRIDE_J;
      bf16x8 b0 = *(const bf16x8*)(bp);
      bf16x8 b1 = *(const bf16x8*)(bp + 1024);
      bf16x8 b2 = *(const bf16x8*)(bp + 2048);
      acc[0][0] = __builtin_amdgcn_mfma_f32_16x16x32_bf16(a0, b0, acc[0][0], 0, 0, 0);
      acc[0][1] = __builtin_amdgcn_mfma_f32_16x16x32_bf16(a0, b1, acc[0][1], 0, 0, 0);
      acc[0][2] = __builtin_amdgcn_mfma_f32_16x16x32_bf16(a0, b2, acc[0][2], 0, 0, 0);
      acc[1][0] = __builtin_amdgcn_mfma_f32_16x16x32_bf16(a1, b0, acc[1][0], 0, 0, 0);
      acc[1][1] = __builtin_amdgcn_mfma_f32_16x16x32_bf16(a1, b1, acc[1][1], 0, 0, 0);
      acc[1][2] = __builtin_amdgcn_mfma_f32_16x16x32_bf16(a1, b2, acc[1][2], 0, 0, 0);
      acc[2][0] = __builtin_amdgcn_mfma_f32_16x16x32_bf16(a2, b0, acc[2][0], 0, 0, 0);
      acc[2][1] = __builtin_amdgcn_mfma_f32_16x16x32_bf16(a2, b1, acc[2][1], 0, 0, 0);
      acc[2][2] = __builtin_amdgcn_mfma_f32_16x16x32_bf16(a2, b2, acc[2][2], 0, 0, 0);
      acc[3][0] = __builtin_amdgcn_mfma_f32_16x16x32_bf16(a3, b0, acc[3][0], 0, 0, 0);
      acc[3][1] = __builtin_amdgcn_mfma_f32_16x16x32_bf16(a3, b1, acc[3][1], 0, 0, 0);
      acc[3][2] = __builtin_amdgcn_mfma_f32_16x16x32_bf16(a3, b2, acc[3][2], 0, 0, 0);
    }

    // Epilogue: bias+ELU, BN partials, pooled-window partials.
    const int wlo = t0w / P_;
    const int wbnd = (wlo + 1) * P_;
    float p0[3] = {0.f, 0.f, 0.f}, p1[3] = {0.f, 0.f, 0.f};
#pragma unroll
    for (int m = 0; m < 4; ++m) {
      const int tr = t0w + m * 16 + lg * 4;
#pragma unroll
      for (int i = 0; i < 4; ++i) {
        const int t = tr + i;
        const bool tv = (t < TO);
#pragma unroll
        for (int nt = 0; nt < 3; ++nt) {
          const float v = acc[m][nt][i] + bv[nt];
          const float y = v > 0.f ? v : expm1f(v);
          if (tv) {
            sY[nt] += y;
            sY2[nt] += y * y;
            if (t < NW * P_) {
              if (t < wbnd)
                p0[nt] += y;
              else
                p1[nt] += y;
            }
          }
        }
      }
    }
#pragma unroll
    for (int nt = 0; nt < 3; ++nt) {
      p0[nt] += __shfl_xor(p0[nt], 16, 64);
      p0[nt] += __shfl_xor(p0[nt], 32, 64);
      p1[nt] += __shfl_xor(p1[nt], 16, 64);
      p1[nt] += __shfl_xor(p1[nt], 32, 64);
      const int k = nt * 16 + l15;
      if (lane < 16 && k < K_) {
        float* pb = pooled + (size_t)b * FCIN + k * NW;
        if (wlo <= 8 && p0[nt] != 0.f) atomicAdd(&pb[wlo], p0[nt]);
        if (wlo + 1 <= 8 && p1[nt] != 0.f) atomicAdd(&pb[wlo + 1], p1[nt]);
      }
    }
  }

#pragma unroll
  for (int nt = 0; nt < 3; ++nt) {
    float a = sY[nt], q2 = sY2[nt];
    a += __shfl_xor(a, 16, 64);
    a += __shfl_xor(a, 32, 64);
    q2 += __shfl_xor(q2, 16, 64);
    q2 += __shfl_xor(q2, 32, 64);
    const int k = nt * 16 + l15;
    if (lane < 16 && k < K_) {
      part_sum[(size_t)k * NBLK + b * 8 + wv] = a;
      part_sq[(size_t)k * NBLK + b * 8 + wv] = q2;
    }
  }
}

__global__ __launch_bounds__(256) void stats_kernel(
    const float* __restrict__ part_sum, const float* __restrict__ part_sq,
    const float* __restrict__ gamma, const float* __restrict__ beta,
    float* __restrict__ ss) {
  const int k = blockIdx.x;
  float s = 0.f, q = 0.f;
  for (int i = threadIdx.x; i < NBLK; i += 256) {
    s += part_sum[(size_t)k * NBLK + i];
    q += part_sq[(size_t)k * NBLK + i];
  }
  s = waveReduceSum(s);
  q = waveReduceSum(q);
  __shared__ float ls[4], lq[4];
  const int wave = threadIdx.x >> 6, lane = threadIdx.x & 63;
  if (lane == 0) {
    ls[wave] = s;
    lq[wave] = q;
  }
  __syncthreads();
  if (threadIdx.x == 0) {
    const float S = ls[0] + ls[1] + ls[2] + ls[3];
    const float Q = lq[0] + lq[1] + lq[2] + lq[3];
    const float N = (float)B_ * (float)TO;
    const float mean = S / N;
    const float var = Q / N - mean * mean;
    const float sc = gamma[k] / sqrtf(var + 1e-5f);
    ss[k] = sc;
    ss[K_ + k] = beta[k] - mean * sc;
  }
}

__global__ __launch_bounds__(256) void fc_kernel(
    const float* __restrict__ pooled, const float* __restrict__ ss,
    const float* __restrict__ fc_w, const float* __restrict__ fc_b,
    float* __restrict__ out) {
  const int bb = blockIdx.x;
  const int n = threadIdx.x >> 6;
  const int lane = threadIdx.x & 63;
  float acc = 0.f;
  for (int i = lane; i < FCIN; i += 64) {
    const int k = i / NW;
    const float y = pooled[(size_t)bb * FCIN + i] * (1.f / (float)P_) * ss[k] + ss[K_ + k];
    acc = fmaf(y, fc_w[n * FCIN + i], acc);
  }
  acc = waveReduceSum(acc);
  if (lane == 0) out[bb * NOUT + n] = acc + fc_b[n];
}

extern "C" void kernel_launch(void* const* d_in, const int* in_sizes, int n_in,
                              void* d_out, int out_size, void* d_ws, size_t ws_size,
                              hipStream_t stream) {
  const float* x = (const float*)d_in[0];
  const float* W = (const float*)d_in[1];
  const float* bias = (const float*)d_in[2];
  const float* gamma = (const float*)d_in[3];
  const float* beta = (const float*)d_in[4];
  const float* fc_w = (const float*)d_in[5];
  const float* fc_b = (const float*)d_in[6];
  float* out = (float*)d_out;

  char* ws = (char*)d_ws;
  float* pooled = (float*)ws;                              // 512*360*4 = 737280
  float* part_sum = (float*)(ws + 737280);                 // 40*4096*4 = 655360
  float* part_sq = (float*)(ws + 1392640);                 // 655360
  unsigned short* WBg = (unsigned short*)(ws + 2048000);   // 9*76800 = 691200
  float* ss = (float*)(ws + 2739200);                      // 320

  hipFuncSetAttribute((const void*)conv_kernel,
                      hipFuncAttributeMaxDynamicSharedMemorySize, LDS_TOTAL);

  hipMemsetAsync(pooled, 0, 737280, stream);
  wconv_kernel<<<9 * KS_, 256, 0, stream>>>(W, WBg);
  conv_kernel<<<B_, 512, LDS_TOTAL, stream>>>(x, WBg, bias, pooled, part_sum, part_sq);
  stats_kernel<<<K_, 256, 0, stream>>>(part_sum, part_sq, gamma, beta, ss);
  fc_kernel<<<B_, 256, 0, stream>>>(pooled, ss, fc_w, fc_b, out);
}

// Round 3
// 87.738 us; speedup vs baseline: 7.8357x; 1.2811x over previous
//
#include <hip/hip_runtime.h>
#include <hip/hip_bf16.h>

#define B_ 512
#define C_ 22
#define TIN 1001
#define K_ 40
#define KS_ 25
#define TO 976
#define P_ 100
#define NW 9
#define NOUT 4
#define FCIN 360

#define HALF 488
#define XROWS 536
#define ZROWS 73
#define XT_ALL (XROWS + ZROWS) /* 609 */
#define RB 48                  /* row bytes: 24 bf16 c-slots */
#define WB_OFF 0
#define WB_BYTES (KS_ * K_ * RB) /* 48000 */
#define XT_OFF WB_BYTES
#define XT_BYTES (XT_ALL * RB)      /* 29232 */
#define ZBASE (XT_OFF + XROWS * RB) /* zero arena: rows 536..608 */
#define RED_OFF (XT_OFF + XT_BYTES) /* 77232 */
#define RED_BYTES (K_ * 8 * 2 * 4)  /* 2560 */
#define LDS_TOTAL (RED_OFF + RED_BYTES) /* 79792 -> 2 blocks/CU */
#define NBLK2 1024

typedef __attribute__((ext_vector_type(8))) short bf16x8;
typedef __attribute__((ext_vector_type(4))) float f32x4;
typedef __attribute__((ext_vector_type(4))) int i32x4;

__device__ __forceinline__ float waveReduceSum(float v) {
#pragma unroll
  for (int m = 32; m >= 1; m >>= 1) v += __shfl_xor(v, m, 64);
  return v;
}

__device__ __forceinline__ unsigned short f2bf(float f) {
  __hip_bfloat16 h = __float2bfloat16(f);
  return *reinterpret_cast<unsigned short*>(&h);
}

// W[s][n][c][j] fp32 -> WBg[s][j][n][chunk] bf16, rows of 24 elems (48 B),
// logical chunk lq (c = lq*8+e, c>=22 zero) stored at phys (lq+((n>>3)&1))%3.
__global__ __launch_bounds__(128) void wconv_kernel(const float* __restrict__ W,
                                                    unsigned short* __restrict__ WBg) {
  const int s = blockIdx.x / KS_;
  const int j = blockIdx.x % KS_;
  const int tid = threadIdx.x;
  if (tid >= 120) return;
  const int n = tid / 3;
  const int lq = tid % 3;
  int ph = lq + ((n >> 3) & 1);
  if (ph >= 3) ph -= 3;
  union {
    unsigned short u[8];
    i32x4 v;
  } pk;
#pragma unroll
  for (int e = 0; e < 8; ++e) {
    const int c = lq * 8 + e;
    float v = 0.f;
    if (c < C_) v = W[(((size_t)s * K_ + n) * C_ + c) * KS_ + j];
    pk.u[e] = f2bf(v);
  }
  *(i32x4*)(WBg + ((size_t)(s * KS_ + j) * K_ + n) * 24 + ph * 8) = pk.v;
}

#define MFMA_SET(A0, A1, A2, A3, Bb0, Bb1, Bb2)                                \
  do {                                                                         \
    acc[0][0] = __builtin_amdgcn_mfma_f32_16x16x32_bf16(A0, Bb0, acc[0][0], 0, 0, 0); \
    acc[0][1] = __builtin_amdgcn_mfma_f32_16x16x32_bf16(A0, Bb1, acc[0][1], 0, 0, 0); \
    acc[0][2] = __builtin_amdgcn_mfma_f32_16x16x32_bf16(A0, Bb2, acc[0][2], 0, 0, 0); \
    acc[1][0] = __builtin_amdgcn_mfma_f32_16x16x32_bf16(A1, Bb0, acc[1][0], 0, 0, 0); \
    acc[1][1] = __builtin_amdgcn_mfma_f32_16x16x32_bf16(A1, Bb1, acc[1][1], 0, 0, 0); \
    acc[1][2] = __builtin_amdgcn_mfma_f32_16x16x32_bf16(A1, Bb2, acc[1][2], 0, 0, 0); \
    acc[2][0] = __builtin_amdgcn_mfma_f32_16x16x32_bf16(A2, Bb0, acc[2][0], 0, 0, 0); \
    acc[2][1] = __builtin_amdgcn_mfma_f32_16x16x32_bf16(A2, Bb1, acc[2][1], 0, 0, 0); \
    acc[2][2] = __builtin_amdgcn_mfma_f32_16x16x32_bf16(A2, Bb2, acc[2][2], 0, 0, 0); \
    acc[3][0] = __builtin_amdgcn_mfma_f32_16x16x32_bf16(A3, Bb0, acc[3][0], 0, 0, 0); \
    acc[3][1] = __builtin_amdgcn_mfma_f32_16x16x32_bf16(A3, Bb1, acc[3][1], 0, 0, 0); \
    acc[3][2] = __builtin_amdgcn_mfma_f32_16x16x32_bf16(A3, Bb2, acc[3][2], 0, 0, 0); \
  } while (0)

#define LOADJ(A0, A1, A2, A3, Bb0, Bb1, Bb2, TBJ, JA0, JA1, JB, EXTRA_A, EXTRA_B) \
  do {                                                                         \
    const int bit_ = ((TBJ) >> 3) & 1;                                         \
    const char* ap_ = sm + (bit_ ? (JA1) : (JA0)) + (EXTRA_A);                 \
    A0 = *(const bf16x8*)(ap_);                                                \
    A1 = *(const bf16x8*)(ap_ + 768);                                          \
    A2 = *(const bf16x8*)(ap_ + 1536);                                         \
    A3 = *(const bf16x8*)(ap_ + 2304);                                         \
    const char* bp_ = sm + (JB) + (EXTRA_B);                                   \
    Bb0 = *(const bf16x8*)(bp_);                                               \
    Bb1 = *(const bf16x8*)(bp_ + 768);                                         \
    Bb2 = *(const bf16x8*)(bp_ + 1536);                                        \
  } while (0)

// grid: 1024 blocks = (sample b, half h). 8 waves, wave = 64 rows x 48 cols.
__global__ __launch_bounds__(512, 4) void conv_kernel(
    const float* __restrict__ x, const unsigned short* __restrict__ WBg,
    const float* __restrict__ bias, float* __restrict__ pooled,
    float* __restrict__ part_sum, float* __restrict__ part_sq) {
  extern __shared__ __align__(16) char smem_[];
  char* sm = smem_;
  const int blk = blockIdx.x;
  const int b = blk >> 1;
  const int h = blk & 1;
  const int tid = threadIdx.x;

  int s = (int)rintf(x[(size_t)b * (C_ * TIN) + (TIN - 1)] * 1e-6f) - 1;
  s = __builtin_amdgcn_readfirstlane(min(max(s, 0), 8));

  // ---- stage weights (48 KB linear copy; global already row-swizzled) ----
  {
    const i32x4* src = (const i32x4*)(WBg + (size_t)s * (WB_BYTES / 2));
    for (int off = tid; off < WB_BYTES / 16; off += 512)
      *(i32x4*)(sm + WB_OFF + off * 16) = src[off];
  }
  // ---- stage xT (transpose + bf16 + row-swizzle) + zero arena ----
  {
    const float* xb = x + (size_t)b * (C_ * TIN);
    const int tgbase = h * HALF;
    for (int task = tid; task < 3 * XT_ALL; task += 512) {
      const int lq = task / XT_ALL;
      const int trow = task - lq * XT_ALL;
      const int tg = tgbase + trow;
      int ph = lq + ((trow >> 3) & 1);
      if (ph >= 3) ph -= 3;
      union {
        unsigned short u[8];
        i32x4 v;
      } pk;
#pragma unroll
      for (int e = 0; e < 8; ++e) {
        const int c = lq * 8 + e;
        float v = 0.f;
        if (c < C_ && trow < XROWS && tg < TIN - 1) v = xb[c * TIN + tg];
        pk.u[e] = f2bf(v);
      }
      *(i32x4*)(sm + XT_OFF + trow * RB + ph * 16) = pk.v;
    }
  }
  __syncthreads();

  const int lane = tid & 63;
  const int wv = tid >> 6;
  const int l15 = lane & 15;
  const int lg = lane >> 4;
  const int t0l = wv * 64;
  const int tb = t0l + l15;  // A base row (local)

  // A base addresses for the two swizzle states (lg==3 -> zero arena).
  int aj0, aj1;
  if (lg < 3) {
    int s1 = lg + 1;
    if (s1 >= 3) s1 -= 3;
    aj0 = XT_OFF + tb * RB + lg * 16;
    aj1 = XT_OFF + tb * RB + s1 * 16;
  } else {
    aj0 = aj1 = ZBASE;
  }
  // B base (one reg; nt offsets are +768 immediates). lg==3 reads finite
  // garbage (annihilated by A==0); n>=40 overflow reads stay in-bounds.
  const int bitn = (l15 >> 3) & 1;
  int pb = lg + bitn;
  if (pb >= 3) pb -= 3;
  const int bbase = WB_OFF + l15 * RB + pb * 16;

  f32x4 acc[4][3];
#pragma unroll
  for (int m = 0; m < 4; ++m)
#pragma unroll
    for (int nt = 0; nt < 3; ++nt) acc[m][nt] = (f32x4){0.f, 0.f, 0.f, 0.f};

  int ja0 = aj0, ja1 = aj1, jb = bbase;
  bf16x8 a00, a01, a02, a03, b00, b01, b02;
  bf16x8 a10, a11, a12, a13, b10, b11, b12;

  LOADJ(a00, a01, a02, a03, b00, b01, b02, tb, ja0, ja1, jb, 0, 0);
  for (int j = 0; j < 24; j += 2) {
    LOADJ(a10, a11, a12, a13, b10, b11, b12, tb + j + 1, ja0, ja1, jb, 48, 1920);
    MFMA_SET(a00, a01, a02, a03, b00, b01, b02);
    ja0 += 96;
    ja1 += 96;
    jb += 3840;
    LOADJ(a00, a01, a02, a03, b00, b01, b02, tb + j + 2, ja0, ja1, jb, 0, 0);
    MFMA_SET(a10, a11, a12, a13, b10, b11, b12);
  }
  MFMA_SET(a00, a01, a02, a03, b00, b01, b02);  // j = 24

  // ---- epilogue: bias + ELU, BN partials, pooled-window partials ----
  float bv[3];
#pragma unroll
  for (int nt = 0; nt < 3; ++nt) {
    const int k = nt * 16 + l15;
    bv[nt] = bias[s * K_ + (k < K_ ? k : 0)];
  }
  const int t0g = h * HALF + t0l;
  const int wlo = t0g / P_;
  const int wb1 = (wlo + 1) * P_;
  float sY[3] = {0.f, 0.f, 0.f}, sY2[3] = {0.f, 0.f, 0.f};
  float p0[3] = {0.f, 0.f, 0.f}, p1[3] = {0.f, 0.f, 0.f};
#pragma unroll
  for (int m = 0; m < 4; ++m) {
    const int rl = t0l + m * 16 + lg * 4;
#pragma unroll
    for (int i = 0; i < 4; ++i) {
      const int tl = rl + i;           // local output row
      const bool valid = (tl < HALF);  // halves tile [0,976) exactly
      const int tg = h * HALF + tl;
#pragma unroll
      for (int nt = 0; nt < 3; ++nt) {
        const float v = acc[m][nt][i] + bv[nt];
        const float y = v > 0.f ? v : expm1f(v);
        if (valid) {
          sY[nt] += y;
          sY2[nt] += y * y;
          if (tg < wb1)
            p0[nt] += y;
          else
            p1[nt] += y;
        }
      }
    }
  }
#pragma unroll
  for (int nt = 0; nt < 3; ++nt) {
    p0[nt] += __shfl_xor(p0[nt], 16, 64);
    p0[nt] += __shfl_xor(p0[nt], 32, 64);
    p1[nt] += __shfl_xor(p1[nt], 16, 64);
    p1[nt] += __shfl_xor(p1[nt], 32, 64);
    float sy = sY[nt] + __shfl_xor(sY[nt], 16, 64);
    sy += __shfl_xor(sy, 32, 64);
    float sq = sY2[nt] + __shfl_xor(sY2[nt], 16, 64);
    sq += __shfl_xor(sq, 32, 64);
    const int k = nt * 16 + l15;
    if (lane < 16 && k < K_) {
      float* pb2 = pooled + (size_t)b * FCIN + k * NW;
      if (wlo <= 8 && p0[nt] != 0.f) atomicAdd(&pb2[wlo], p0[nt]);
      if (wlo + 1 <= 8 && p1[nt] != 0.f) atomicAdd(&pb2[wlo + 1], p1[nt]);
      float* red = (float*)(sm + RED_OFF);
      red[k * 8 + wv] = sy;
      red[K_ * 8 + k * 8 + wv] = sq;
    }
  }
  __syncthreads();
  if (tid < K_) {
    const float* red = (const float*)(sm + RED_OFF);
    float a = 0.f, q = 0.f;
#pragma unroll
    for (int i = 0; i < 8; ++i) {
      a += red[tid * 8 + i];
      q += red[K_ * 8 + tid * 8 + i];
    }
    part_sum[(size_t)tid * NBLK2 + blk] = a;
    part_sq[(size_t)tid * NBLK2 + blk] = q;
  }
}

__global__ __launch_bounds__(256) void stats_kernel(
    const float* __restrict__ part_sum, const float* __restrict__ part_sq,
    const float* __restrict__ gamma, const float* __restrict__ beta,
    float* __restrict__ ss) {
  const int k = blockIdx.x;
  float s = 0.f, q = 0.f;
  for (int i = threadIdx.x; i < NBLK2; i += 256) {
    s += part_sum[(size_t)k * NBLK2 + i];
    q += part_sq[(size_t)k * NBLK2 + i];
  }
  s = waveReduceSum(s);
  q = waveReduceSum(q);
  __shared__ float ls[4], lq[4];
  const int wave = threadIdx.x >> 6, lane = threadIdx.x & 63;
  if (lane == 0) {
    ls[wave] = s;
    lq[wave] = q;
  }
  __syncthreads();
  if (threadIdx.x == 0) {
    const float S = ls[0] + ls[1] + ls[2] + ls[3];
    const float Q = lq[0] + lq[1] + lq[2] + lq[3];
    const float N = (float)B_ * (float)TO;
    const float mean = S / N;
    const float var = Q / N - mean * mean;
    const float sc = gamma[k] / sqrtf(var + 1e-5f);
    ss[k] = sc;
    ss[K_ + k] = beta[k] - mean * sc;
  }
}

__global__ __launch_bounds__(256) void fc_kernel(
    const float* __restrict__ pooled, const float* __restrict__ ss,
    const float* __restrict__ fc_w, const float* __restrict__ fc_b,
    float* __restrict__ out) {
  const int bb = blockIdx.x;
  const int n = threadIdx.x >> 6;
  const int lane = threadIdx.x & 63;
  float acc = 0.f;
  for (int i = lane; i < FCIN; i += 64) {
    const int k = i / NW;
    const float y = pooled[(size_t)bb * FCIN + i] * (1.f / (float)P_) * ss[k] + ss[K_ + k];
    acc = fmaf(y, fc_w[n * FCIN + i], acc);
  }
  acc = waveReduceSum(acc);
  if (lane == 0) out[bb * NOUT + n] = acc + fc_b[n];
}

extern "C" void kernel_launch(void* const* d_in, const int* in_sizes, int n_in,
                              void* d_out, int out_size, void* d_ws, size_t ws_size,
                              hipStream_t stream) {
  const float* x = (const float*)d_in[0];
  const float* W = (const float*)d_in[1];
  const float* bias = (const float*)d_in[2];
  const float* gamma = (const float*)d_in[3];
  const float* beta = (const float*)d_in[4];
  const float* fc_w = (const float*)d_in[5];
  const float* fc_b = (const float*)d_in[6];
  float* out = (float*)d_out;

  char* ws = (char*)d_ws;
  float* pooled = (float*)ws;                            // 512*360*4 = 737280
  float* part_sum = (float*)(ws + 737280);               // 40*1024*4 = 163840
  float* part_sq = (float*)(ws + 901120);                // 163840
  unsigned short* WBg = (unsigned short*)(ws + 1064960); // 9*48000 = 432000
  float* ss = (float*)(ws + 1496960);                    // 320

  hipFuncSetAttribute((const void*)conv_kernel,
                      hipFuncAttributeMaxDynamicSharedMemorySize, LDS_TOTAL);

  hipMemsetAsync(pooled, 0, 737280, stream);
  wconv_kernel<<<9 * KS_, 128, 0, stream>>>(W, WBg);
  conv_kernel<<<NBLK2, 512, LDS_TOTAL, stream>>>(x, WBg, bias, pooled, part_sum, part_sq);
  stats_kernel<<<K_, 256, 0, stream>>>(part_sum, part_sq, gamma, beta, ss);
  fc_kernel<<<B_, 256, 0, stream>>>(pooled, ss, fc_w, fc_b, out);
}